// Round 1
// baseline (3751.653 us; speedup 1.0000x reference)
//
#include <hip/hip_runtime.h>

#define N 512
#define C 256
#define TJ 16

// ---------------------------------------------------------------------------
// Kernel 1: per-edge scores.
//   e[j][c] = n[i][c] * n[j][c] * s[i][j][c]
//   qhat[d] = Wq[d,:] . e[j,:] + bq[d]   (khat analog)
//   scores[i][j] = sum_d qhat*khat*v[i][j][d]^2 / sqrt(C)
// Block: 256 threads (thread = output channel d), handles one (i, 16-j tile).
// ---------------------------------------------------------------------------
__global__ __launch_bounds__(256) void k_scores(
    const float* __restrict__ n_g, const float* __restrict__ s_g,
    const float* __restrict__ v_g,
    const float* __restrict__ Wq, const float* __restrict__ bq,
    const float* __restrict__ Wk, const float* __restrict__ bk,
    float* __restrict__ scores)
{
    __shared__ float e_lds[TJ][C];
    __shared__ float part[4][TJ];
    const int i  = blockIdx.x;
    const int jb = blockIdx.y * TJ;
    const int t  = threadIdx.x;        // = channel d
    const int lane = t & 63, wid = t >> 6;

    const float ni = n_g[i * C + t];
    #pragma unroll
    for (int j = 0; j < TJ; ++j) {
        const int jj = jb + j;
        e_lds[j][t] = ni * n_g[jj * C + t] * s_g[((size_t)i * N + jj) * C + t];
    }
    __syncthreads();

    float accq[TJ], acck[TJ];
    const float bqd = bq[t], bkd = bk[t];
    #pragma unroll
    for (int j = 0; j < TJ; ++j) { accq[j] = bqd; acck[j] = bkd; }

    const float4* wq4 = (const float4*)(Wq + (size_t)t * C);
    const float4* wk4 = (const float4*)(Wk + (size_t)t * C);
    for (int c4 = 0; c4 < C / 4; ++c4) {
        const float4 wq = wq4[c4];
        const float4 wk = wk4[c4];
        #pragma unroll
        for (int j = 0; j < TJ; ++j) {
            const float4 ev = *(const float4*)&e_lds[j][c4 * 4];
            accq[j] += wq.x*ev.x + wq.y*ev.y + wq.z*ev.z + wq.w*ev.w;
            acck[j] += wk.x*ev.x + wk.y*ev.y + wk.z*ev.z + wk.w*ev.w;
        }
    }

    #pragma unroll
    for (int j = 0; j < TJ; ++j) {
        const int jj = jb + j;
        const float vv = v_g[((size_t)i * N + jj) * C + t];
        float r = accq[j] * acck[j] * vv * vv;
        #pragma unroll
        for (int off = 32; off > 0; off >>= 1)
            r += __shfl_down(r, off, 64);
        if (lane == 0) part[wid][j] = r;
    }
    __syncthreads();
    if (t < TJ) {
        const float ssum = part[0][t] + part[1][t] + part[2][t] + part[3][t];
        scores[(size_t)i * N + jb + t] = ssum * (1.0f / 16.0f);  // 1/sqrt(256)
    }
}

// ---------------------------------------------------------------------------
// Kernel 2: row softmax, in place (512 cols, 256 threads -> 2 each).
// ---------------------------------------------------------------------------
__global__ __launch_bounds__(256) void k_softmax(float* __restrict__ buf)
{
    __shared__ float red[4];
    const int i = blockIdx.x;
    const int t = threadIdx.x;
    const int lane = t & 63, wid = t >> 6;

    const float a = buf[(size_t)i * N + t];
    const float b = buf[(size_t)i * N + t + 256];
    float m = fmaxf(a, b);
    #pragma unroll
    for (int off = 32; off > 0; off >>= 1)
        m = fmaxf(m, __shfl_xor(m, off, 64));
    if (lane == 0) red[wid] = m;
    __syncthreads();
    m = fmaxf(fmaxf(red[0], red[1]), fmaxf(red[2], red[3]));

    const float ea = __expf(a - m), eb = __expf(b - m);
    float ssum = ea + eb;
    #pragma unroll
    for (int off = 32; off > 0; off >>= 1)
        ssum += __shfl_xor(ssum, off, 64);
    __syncthreads();               // red reuse
    if (lane == 0) red[wid] = ssum;
    __syncthreads();
    const float inv = 1.0f / (red[0] + red[1] + red[2] + red[3]);
    buf[(size_t)i * N + t]       = ea * inv;
    buf[(size_t)i * N + t + 256] = eb * inv;
}

// ---------------------------------------------------------------------------
// Kernel 3: x[i][d] = sum_j attn[i][j] * (Wv e + bv)[d] * v[i][j][d],
// then residual + row L2-normalize. One block per row i, thread = d.
// ---------------------------------------------------------------------------
__global__ __launch_bounds__(256) void k_out(
    const float* __restrict__ n_g, const float* __restrict__ s_g,
    const float* __restrict__ v_g,
    const float* __restrict__ Wv, const float* __restrict__ bv,
    const float* __restrict__ attn, float* __restrict__ out)
{
    __shared__ float e_lds[TJ][C];
    __shared__ float part[4];
    const int i = blockIdx.x;
    const int t = threadIdx.x;
    const int lane = t & 63, wid = t >> 6;

    const float ni  = n_g[i * C + t];
    const float bvd = bv[t];
    const float4* wv4 = (const float4*)(Wv + (size_t)t * C);
    float xacc = 0.0f;

    for (int jt = 0; jt < N / TJ; ++jt) {
        const int jb = jt * TJ;
        __syncthreads();           // done with previous tile's e_lds
        #pragma unroll
        for (int j = 0; j < TJ; ++j) {
            const int jj = jb + j;
            e_lds[j][t] = ni * n_g[jj * C + t] * s_g[((size_t)i * N + jj) * C + t];
        }
        __syncthreads();

        float accv[TJ];
        #pragma unroll
        for (int j = 0; j < TJ; ++j) accv[j] = bvd;
        for (int c4 = 0; c4 < C / 4; ++c4) {
            const float4 wv = wv4[c4];
            #pragma unroll
            for (int j = 0; j < TJ; ++j) {
                const float4 ev = *(const float4*)&e_lds[j][c4 * 4];
                accv[j] += wv.x*ev.x + wv.y*ev.y + wv.z*ev.z + wv.w*ev.w;
            }
        }
        #pragma unroll
        for (int j = 0; j < TJ; ++j) {
            const int jj = jb + j;
            const float a  = attn[(size_t)i * N + jj];
            const float vd = v_g[((size_t)i * N + jj) * C + t];
            xacc += a * accv[j] * vd;
        }
    }

    const float x = xacc + ni;
    float sq = x * x;
    #pragma unroll
    for (int off = 32; off > 0; off >>= 1)
        sq += __shfl_xor(sq, off, 64);
    if (lane == 0) part[wid] = sq;
    __syncthreads();
    const float nrm = sqrtf(part[0] + part[1] + part[2] + part[3]);
    out[i * C + t] = x / nrm;
}

extern "C" void kernel_launch(void* const* d_in, const int* in_sizes, int n_in,
                              void* d_out, int out_size, void* d_ws, size_t ws_size,
                              hipStream_t stream)
{
    const float* n_g = (const float*)d_in[0];
    const float* s_g = (const float*)d_in[1];
    const float* v_g = (const float*)d_in[2];
    const float* Wq  = (const float*)d_in[3];
    const float* bq  = (const float*)d_in[4];
    const float* Wk  = (const float*)d_in[5];
    const float* bk  = (const float*)d_in[6];
    const float* Wv  = (const float*)d_in[7];
    const float* bv  = (const float*)d_in[8];
    float* out = (float*)d_out;
    float* buf = (float*)d_ws;     // N*N fp32 scores -> attn (1 MB)

    k_scores <<<dim3(N, N / TJ), 256, 0, stream>>>(n_g, s_g, v_g, Wq, bq, Wk, bk, buf);
    k_softmax<<<N,               256, 0, stream>>>(buf);
    k_out    <<<N,               256, 0, stream>>>(n_g, s_g, v_g, Wv, bv, buf, out);
}